// Round 22
// baseline (427.416 us; speedup 1.0000x reference)
//
#include <hip/hip_runtime.h>

typedef unsigned short u16;
typedef unsigned int   u32;

#define DIMC 192
#define NWIN 343
#define LTOK 21952
#define ROWSZ 43904            // B * L rows
#define TOTE 8429568           // ROWSZ * DIMC
#define QSCALE 0.17677669529663689f
#define EPSF 1e-5f
#define MLPBLK 1372            // ROWSZ/32

typedef __attribute__((ext_vector_type(8))) short bf16x8v;
typedef __attribute__((ext_vector_type(4))) float f32x4v;

__device__ __forceinline__ float bu(u16 v){ union{u32 u; float f;} x; x.u = ((u32)v)<<16; return x.f; }
__device__ __forceinline__ float lo16(u32 p){ union{u32 u; float f;} x; x.u = p<<16; return x.f; }
__device__ __forceinline__ float hi16(u32 p){ union{u32 u; float f;} x; x.u = p & 0xffff0000u; return x.f; }
__device__ __forceinline__ u16 fb(float f){
  union{float ff; u32 u;} x; x.ff = f;
  u32 r = (x.u + 0x7fffu + ((x.u>>16)&1u)) >> 16;
  return (u16)r;
}
__device__ __forceinline__ float gelu_f(float x){ return 0.5f*x*(1.0f + erff(x*0.70710678118654752f)); }

__device__ __forceinline__ f32x4v mfma_bf16(bf16x8v a, bf16x8v b, f32x4v c){
  return __builtin_amdgcn_mfma_f32_16x16x32_bf16(a, b, c, 0, 0, 0);
}

// windowed-row -> (batch, token) bijection (shift -3 + partition).
__device__ __forceinline__ void row_to_token(int row, int& b, int& l){
  int bw = row / NWIN, n = row % NWIN;
  b = bw >> 6; int wi = bw & 63;
  int sd = (wi>>4)*7      + n/49;
  int sh = ((wi>>2)&3)*7  + (n/7)%7;
  int sw = (wi&3)*7       + n%7;
  int d = sd+3; if(d>=28) d-=28;
  int h = sh+3; if(h>=28) h-=28;
  int w = sw+3; if(w>=28) w-=28;
  l = d*784 + h*28 + w;
}

// ---------------- weight pre-pack into B-fragment order (bf16) ----------------
template<int TR>
__global__ __launch_bounds__(256) void pack_w(const float* __restrict__ W, u16* __restrict__ dst,
                                              int K, int N){
  int gid = blockIdx.x*256 + threadIdx.x;
  if(gid >= K*N) return;
  int k = gid / N, n = gid - k*N;
  float v = TR ? W[(long)n*K + k] : W[(long)k*N + n];
  int nt = n >> 4, ks = k >> 5;
  int l  = (((k>>3)&3)<<4) | (n&15);
  int j  = k & 7;
  int KS = K >> 5;
  dst[((((nt*KS + ks)<<6) + l)<<3) + j] = fb(v);
}

// ---------------- depthwise weight transpose: [192][27] -> [27][192] ----------------
__global__ __launch_bounds__(256) void pack_dwk(const float* __restrict__ k1, const float* __restrict__ k2,
                                                float* __restrict__ d1, float* __restrict__ d2){
  int gid = blockIdx.x*256 + threadIdx.x;
  if(gid < 5184){
    int tap = gid/192, c = gid - tap*192;
    d1[gid] = k1[c*27 + tap];
    d2[gid] = k2[c*27 + tap];
  }
}

// ---------------- fused LN1 + QKV GEMM (q pre-scaled by QSCALE) ----------------
__global__ __launch_bounds__(256) void gemm_qkv_ln(const float* __restrict__ x, const float* __restrict__ g,
                                                   const float* __restrict__ bb, const u16* __restrict__ Wp,
                                                   const float* __restrict__ bias, u16* __restrict__ out){
  __shared__ float Xs[32*192];
  __shared__ u16 As[32*192];
  __shared__ long tb_l[32];
  const int tid = threadIdx.x;
  const int w = tid>>6, l = tid&63;
  const int lm = l&15, lh = l>>4;
  const long row0 = (long)blockIdx.x*32;

  if(tid < 32){
    int b_, lt; row_to_token((int)(row0+tid), b_, lt);
    tb_l[tid] = ((long)b_*LTOK + lt)*DIMC;
  }
  __syncthreads();

  #pragma unroll
  for(int c=0;c<24;c++){
    int idx = tid + c*256;
    int row = idx/192, col = idx - row*192;
    Xs[idx] = x[tb_l[row] + col];
  }
  __syncthreads();

  for(int rr=0;rr<8;rr++){
    int row = w*8 + rr;
    const float* pr = &Xs[row*192];
    float v0 = pr[l], v1 = pr[l+64], v2 = pr[l+128];
    float s = v0+v1+v2;
    #pragma unroll
    for(int m=1;m<64;m<<=1) s += __shfl_xor(s,m);
    float mean = s*(1.f/192.f);
    float d0=v0-mean, d1=v1-mean, d2=v2-mean;
    float q = d0*d0+d1*d1+d2*d2;
    #pragma unroll
    for(int m=1;m<64;m<<=1) q += __shfl_xor(q,m);
    float rstd = rsqrtf(q*(1.f/192.f)+EPSF);
    *(u16*)((char*)As + ((row*384 + 2*l)       ^ ((row&7)<<4))) = fb(d0*rstd*g[l]     + bb[l]);
    *(u16*)((char*)As + ((row*384 + 2*(l+64))  ^ ((row&7)<<4))) = fb(d1*rstd*g[l+64]  + bb[l+64]);
    *(u16*)((char*)As + ((row*384 + 2*(l+128)) ^ ((row&7)<<4))) = fb(d2*rstd*g[l+128] + bb[l+128]);
  }
  __syncthreads();

  f32x4v acc[9][2];
  const f32x4v z4 = {0.f,0.f,0.f,0.f};
  #pragma unroll
  for(int i=0;i<9;i++){ acc[i][0]=z4; acc[i][1]=z4; }

  #pragma unroll
  for(int ks=0;ks<6;ks++){
    bf16x8v a[2];
    #pragma unroll
    for(int mt=0;mt<2;mt++){
      int row = mt*16 + lm;
      int byte = (row*384 + ks*64 + lh*16) ^ ((row&7)<<4);
      a[mt] = *(const bf16x8v*)((const char*)As + byte);
    }
    #pragma unroll
    for(int i=0;i<9;i++){
      int nt = w*9 + i;
      bf16x8v b = *(const bf16x8v*)(Wp + ((((nt*6 + ks)<<6) + l)<<3));
      acc[i][0] = mfma_bf16(a[0], b, acc[i][0]);
      acc[i][1] = mfma_bf16(a[1], b, acc[i][1]);
    }
  }

  #pragma unroll
  for(int i=0;i<9;i++){
    int n = (w*9 + i)*16 + lm;
    float bv = bias[n];
    #pragma unroll
    for(int mt=0;mt<2;mt++){
      #pragma unroll
      for(int r=0;r<4;r++){
        long mrow = row0 + mt*16 + lh*4 + r;
        float v = acc[i][mt][r] + bv;
        if(n < 192) v *= QSCALE;
        out[mrow*576 + n] = fb(v);
      }
    }
  }
}

// ---------------- fused proj GEMM + residual + LN2 ----------------
__global__ __launch_bounds__(256) void gemm_proj_ln(const u16* __restrict__ A, const u16* __restrict__ Wp,
                                                    const float* __restrict__ bias, const float* __restrict__ resid,
                                                    const float* __restrict__ g, const float* __restrict__ bb,
                                                    u16* __restrict__ x1o, u16* __restrict__ xmo){
  __shared__ u16 As[32*192];
  __shared__ float Vs2[32*200];
  __shared__ long tb_l[32];
  const int tid = threadIdx.x;
  const int w = tid>>6, l = tid&63;
  const int lm = l&15, lh = l>>4;
  const long row0 = (long)blockIdx.x*32;

  if(tid < 32){
    int b_, lt; row_to_token((int)(row0+tid), b_, lt);
    tb_l[tid] = ((long)b_*LTOK + lt)*DIMC;
  }
  {
    const uint4* src = (const uint4*)(A + row0*192);
    #pragma unroll
    for(int c=0;c<3;c++){
      int cz = tid + c*256;
      int row = cz/24;
      int byte = (cz*16) ^ ((row&7)<<4);
      *(uint4*)((char*)As + byte) = src[cz];
    }
  }
  __syncthreads();

  f32x4v acc[3][2];
  const f32x4v z4 = {0.f,0.f,0.f,0.f};
  #pragma unroll
  for(int i=0;i<3;i++){ acc[i][0]=z4; acc[i][1]=z4; }

  #pragma unroll
  for(int ks=0;ks<6;ks++){
    bf16x8v a[2];
    #pragma unroll
    for(int mt=0;mt<2;mt++){
      int row = mt*16 + lm;
      int byte = (row*384 + ks*64 + lh*16) ^ ((row&7)<<4);
      a[mt] = *(const bf16x8v*)((const char*)As + byte);
    }
    #pragma unroll
    for(int i=0;i<3;i++){
      int nt = w*3 + i;
      bf16x8v b = *(const bf16x8v*)(Wp + ((((nt*6 + ks)<<6) + l)<<3));
      acc[i][0] = mfma_bf16(a[0], b, acc[i][0]);
      acc[i][1] = mfma_bf16(a[1], b, acc[i][1]);
    }
  }

  #pragma unroll
  for(int i=0;i<3;i++){
    int n = (w*3 + i)*16 + lm;
    float bv = bias[n];
    #pragma unroll
    for(int mt=0;mt<2;mt++){
      #pragma unroll
      for(int r=0;r<4;r++){
        int row = mt*16 + lh*4 + r;
        Vs2[row*200 + n] = acc[i][mt][r] + bv + resid[tb_l[row] + n];
      }
    }
  }
  __syncthreads();

  for(int rr=0;rr<8;rr++){
    int row = w*8 + rr;
    long tb = tb_l[row];
    const float* pr = &Vs2[row*200];
    float v0 = pr[l], v1 = pr[l+64], v2 = pr[l+128];
    float s = v0+v1+v2;
    #pragma unroll
    for(int m=1;m<64;m<<=1) s += __shfl_xor(s,m);
    float mean = s*(1.f/192.f);
    float d0=v0-mean, d1=v1-mean, d2=v2-mean;
    float q = d0*d0+d1*d1+d2*d2;
    #pragma unroll
    for(int m=1;m<64;m<<=1) q += __shfl_xor(q,m);
    float rstd = rsqrtf(q*(1.f/192.f)+EPSF);
    x1o[tb+l]     = fb(v0);
    x1o[tb+l+64]  = fb(v1);
    x1o[tb+l+128] = fb(v2);
    xmo[tb+l]     = fb(d0*rstd*g[l]     + bb[l]);
    xmo[tb+l+64]  = fb(d1*rstd*g[l+64]  + bb[l+64]);
    xmo[tb+l+128] = fb(d2*rstd*g[l+128] + bb[l+128]);
  }
}

// ---------------- MFMA GEMM (pointwise convs): 32 rows/block, K=192 ----------------
template<int NTOT>
__global__ __launch_bounds__(256) void gemm_mfma(const u16* __restrict__ A, const u16* __restrict__ Wp,
                                                 const float* __restrict__ bias, u16* __restrict__ out){
  constexpr int KS  = 6;
  constexpr int NPW = NTOT/64;
  __shared__ u16 As[32*192];
  const int tid = threadIdx.x;
  const int w = tid>>6, l = tid&63;
  const int lm = l&15, lh = l>>4;
  const long row0 = (long)blockIdx.x*32;

  {
    const uint4* src = (const uint4*)(A + row0*192);
    #pragma unroll
    for(int c=0;c<3;c++){
      int cz = tid + c*256;
      int row = cz/24;
      int byte = (cz*16) ^ ((row&7)<<4);
      *(uint4*)((char*)As + byte) = src[cz];
    }
  }
  __syncthreads();

  f32x4v acc[NPW][2];
  const f32x4v z4 = {0.f,0.f,0.f,0.f};
  #pragma unroll
  for(int i=0;i<NPW;i++){ acc[i][0]=z4; acc[i][1]=z4; }

  #pragma unroll
  for(int ks=0;ks<KS;ks++){
    bf16x8v a[2];
    #pragma unroll
    for(int mt=0;mt<2;mt++){
      int row = mt*16 + lm;
      int byte = (row*384 + ks*64 + lh*16) ^ ((row&7)<<4);
      a[mt] = *(const bf16x8v*)((const char*)As + byte);
    }
    #pragma unroll
    for(int i=0;i<NPW;i++){
      int nt = w*NPW + i;
      bf16x8v b = *(const bf16x8v*)(Wp + ((((nt*KS + ks)<<6) + l)<<3));
      acc[i][0] = mfma_bf16(a[0], b, acc[i][0]);
      acc[i][1] = mfma_bf16(a[1], b, acc[i][1]);
    }
  }

  #pragma unroll
  for(int i=0;i<NPW;i++){
    int n = (w*NPW + i)*16 + lm;
    float bv = bias[n];
    #pragma unroll
    for(int mt=0;mt<2;mt++){
      #pragma unroll
      for(int r=0;r<4;r++){
        long mrow = row0 + mt*16 + lh*4 + r;
        out[mrow*NTOT + n] = fb(acc[i][mt][r] + bv);
      }
    }
  }
}

// ---------------- FUSED: mlp (blocks 0..1371) || dw-conv#1 (blocks 1372..2400) ----------------
// Independent work items sharing one launch so dw blocks fill mlp's latency bubbles.
__global__ __launch_bounds__(256) void mlp_dw_fused(const u16* __restrict__ xm,
                                                    const u16* __restrict__ Wp1, const float* __restrict__ b1,
                                                    const u16* __restrict__ Wp2, const float* __restrict__ b2,
                                                    u16* __restrict__ lin_out,
                                                    const float* __restrict__ kwT, const float* __restrict__ dwb,
                                                    u16* __restrict__ conv_out){
  __shared__ char smem[61440];
  const int tid = threadIdx.x;

  if(blockIdx.x < MLPBLK){
    // ================= mlp path (r13-proven structure) =================
    u16* As = (u16*)smem;            // 12288 B
    u16* Hs = (u16*)(smem + 12288);  // 49152 B
    const int w = tid>>6, l = tid&63;
    const int lm = l&15, lh = l>>4;
    const long row0 = (long)blockIdx.x*32;

    {
      const uint4* src = (const uint4*)(xm + row0*192);
      #pragma unroll
      for(int c=0;c<3;c++){
        int cz = tid + c*256;
        int row = cz/24;
        int byte = (cz*16) ^ ((row&7)<<4);
        *(uint4*)((char*)As + byte) = src[cz];
      }
    }
    __syncthreads();

    const f32x4v z4 = {0.f,0.f,0.f,0.f};
    f32x4v acc1[12][2];
    #pragma unroll
    for(int i=0;i<12;i++){ acc1[i][0]=z4; acc1[i][1]=z4; }

    #pragma unroll
    for(int ks=0;ks<6;ks++){
      bf16x8v a[2];
      #pragma unroll
      for(int mt=0;mt<2;mt++){
        int row = mt*16 + lm;
        int byte = (row*384 + ks*64 + lh*16) ^ ((row&7)<<4);
        a[mt] = *(const bf16x8v*)((const char*)As + byte);
      }
      #pragma unroll
      for(int i=0;i<12;i++){
        int nt = w*12 + i;
        bf16x8v b = *(const bf16x8v*)(Wp1 + ((((nt*6 + ks)<<6) + l)<<3));
        acc1[i][0] = mfma_bf16(a[0], b, acc1[i][0]);
        acc1[i][1] = mfma_bf16(a[1], b, acc1[i][1]);
      }
    }

    #pragma unroll
    for(int i=0;i<12;i++){
      int n = (w*12 + i)*16 + lm;
      float bv = b1[n];
      #pragma unroll
      for(int mt=0;mt<2;mt++){
        #pragma unroll
        for(int r=0;r<4;r++){
          int mrow = mt*16 + lh*4 + r;
          float h = gelu_f(acc1[i][mt][r] + bv);
          int byte = (mrow*1536 + n*2) ^ ((mrow&7)<<4);
          *(u16*)((char*)Hs + byte) = fb(h);
        }
      }
    }
    __syncthreads();

    f32x4v acc2[3][2];
    #pragma unroll
    for(int i=0;i<3;i++){ acc2[i][0]=z4; acc2[i][1]=z4; }

    #pragma unroll 4
    for(int ks=0;ks<24;ks++){
      bf16x8v a[2];
      #pragma unroll
      for(int mt=0;mt<2;mt++){
        int row = mt*16 + lm;
        int byte = (row*1536 + ks*64 + lh*16) ^ ((row&7)<<4);
        a[mt] = *(const bf16x8v*)((const char*)Hs + byte);
      }
      #pragma unroll
      for(int i=0;i<3;i++){
        int nt = w*3 + i;
        bf16x8v b = *(const bf16x8v*)(Wp2 + ((((nt*24 + ks)<<6) + l)<<3));
        acc2[i][0] = mfma_bf16(a[0], b, acc2[i][0]);
        acc2[i][1] = mfma_bf16(a[1], b, acc2[i][1]);
      }
    }

    #pragma unroll
    for(int i=0;i<3;i++){
      int n = (w*3 + i)*16 + lm;
      float bv = b2[n];
      #pragma unroll
      for(int mt=0;mt<2;mt++){
        #pragma unroll
        for(int r=0;r<4;r++){
          long mrow = row0 + mt*16 + lh*4 + r;
          lin_out[mrow*192 + n] = fb(acc2[i][mt][r] + bv);
        }
      }
    }
  } else {
    // ================= dw-conv path (dw3v4, r16-proven) =================
    float* wls = (float*)smem;       // 20736 B
    for(int i=tid;i<5184;i+=256) wls[i] = kwT[i];
    __syncthreads();

    int gid = (blockIdx.x - MLPBLK)*256 + tid;
    int c8 = gid % 24;
    int t  = gid / 24;
    int b  = t / 5488; int s = t - b*5488;
    int z  = s / 196;  int r = s - z*196;
    int y  = r / 7;    int x4 = r - y*7;
    int x0 = x4*4;

    float acc[4][8];
    {
      const float4* bp = (const float4*)(dwb + c8*8);
      float4 b0 = bp[0], b1v = bp[1];
      #pragma unroll
      for(int xi=0;xi<4;xi++){
        acc[xi][0]=b0.x; acc[xi][1]=b0.y; acc[xi][2]=b0.z; acc[xi][3]=b0.w;
        acc[xi][4]=b1v.x; acc[xi][5]=b1v.y; acc[xi][6]=b1v.z; acc[xi][7]=b1v.w;
      }
    }

    #pragma unroll
    for(int dz=-1;dz<=1;dz++){
      int zz=z+dz; if((unsigned)zz>=28u) continue;
      #pragma unroll
      for(int dy=-1;dy<=1;dy++){
        int yy=y+dy; if((unsigned)yy>=28u) continue;
        const u16* rowp = xm + (((long)b*LTOK + zz*784 + yy*28)*192) + c8*8;
        uint4 v[6];
        #pragma unroll
        for(int xc=0;xc<6;xc++){
          int xx = x0 + xc - 1;
          if((unsigned)xx < 28u) v[xc] = *(const uint4*)(rowp + (long)xx*192);
          else { v[xc].x=0; v[xc].y=0; v[xc].z=0; v[xc].w=0; }
        }
        #pragma unroll
        for(int dxi=0;dxi<3;dxi++){
          int tap = (dz+1)*9+(dy+1)*3+dxi;
          const float* wp = &wls[tap*192 + c8*8];
          float4 w0 = *(const float4*)wp;
          float4 w1 = *(const float4*)(wp+4);
          #pragma unroll
          for(int xi=0;xi<4;xi++){
            uint4 vv = v[xi+dxi];
            acc[xi][0] = fmaf(lo16(vv.x), w0.x, acc[xi][0]);
            acc[xi][1] = fmaf(hi16(vv.x), w0.y, acc[xi][1]);
            acc[xi][2] = fmaf(lo16(vv.y), w0.z, acc[xi][2]);
            acc[xi][3] = fmaf(hi16(vv.y), w0.w, acc[xi][3]);
            acc[xi][4] = fmaf(lo16(vv.z), w1.x, acc[xi][4]);
            acc[xi][5] = fmaf(hi16(vv.z), w1.y, acc[xi][5]);
            acc[xi][6] = fmaf(lo16(vv.w), w1.z, acc[xi][6]);
            acc[xi][7] = fmaf(hi16(vv.w), w1.w, acc[xi][7]);
          }
        }
      }
    }

    u16* op = conv_out + (((long)b*LTOK + z*784 + y*28 + x0)*192) + c8*8;
    #pragma unroll
    for(int xi=0;xi<4;xi++){
      uint4 o;
      o.x = ((u32)fb(acc[xi][1])<<16) | fb(acc[xi][0]);
      o.y = ((u32)fb(acc[xi][3])<<16) | fb(acc[xi][2]);
      o.z = ((u32)fb(acc[xi][5])<<16) | fb(acc[xi][4]);
      o.w = ((u32)fb(acc[xi][7])<<16) | fb(acc[xi][6]);
      *(uint4*)(op + (long)xi*192) = o;
    }
  }
}

// ---------------- MFMA attention v3' ----------------
__global__ __launch_bounds__(256) void attn_mfma(const u16* __restrict__ qkv, const float* __restrict__ rpb,
                                                 u16* __restrict__ out){
  __shared__ u16 Kf[22*512];
  __shared__ u16 Vt[32*360];
  __shared__ u16 Ps[4][16*200];
  __shared__ u16 rpb_l[2198];
  __shared__ u32 lin_l[352];

  const int tid = threadIdx.x;
  const int bw = blockIdx.x / 6, hh = blockIdx.x % 6;
  const int wi = bw & 63;
  const long rowbase = (long)bw*NWIN;

  for(int i=tid;i<2197;i+=256) rpb_l[i] = fb(rpb[i*6+hh]);
  for(int i2=tid;i2<352;i2+=256){
    u32 v = 0x7FFF0000u;
    if(i2 < 343){
      int jz = i2/49, jr = i2-jz*49, jy = jr/7, jx = jr-jy*7;
      int sd = (wi>>4)*7 + jz, sh2 = ((wi>>2)&3)*7 + jy, sw = (wi&3)*7 + jx;
      int rd = sd<21?0:(sd<25?1:2);
      int rh = sh2<21?0:(sh2<25?1:2);
      int rw = sw<21?0:(sw<25?1:2);
      v = (u32)(jz*169 + jy*13 + jx) | ((u32)(rd*9+rh*3+rw)<<16);
    }
    lin_l[i2] = v;
  }
  for(int p2=tid;p2<288;p2+=256){
    int d = p2/9, j = 343 + p2%9; Vt[d*360 + j] = 0;
  }
  ((u32*)Kf)[21*256 + tid] = 0;
  __syncthreads();

  for(int p = tid; p < 343*16; p += 256){
    int j = p >> 4, dp = p & 15;
    const u32* src = (const u32*)(qkv + (rowbase + j)*576 + hh*32) + dp;
    u32 kk = src[96];
    u32 vv = src[192];
    ((u32*)Kf)[(j>>4)*256 + ((dp>>2)*16 + (j&15))*4 + (dp&3)] = kk;
    Vt[(dp*2)*360 + j]   = (u16)(vv & 0xffffu);
    Vt[(dp*2+1)*360 + j] = (u16)(vv >> 16);
  }
  __syncthreads();

  const int w = tid>>6, l = tid&63;
  const int lm = l&15, lh = l>>4;
  u16* Pw = Ps[w];
  const f32x4v z4 = {0.f,0.f,0.f,0.f};

  for(int it = w; it < 22; it += 4){
    const int i0 = it*16;
    bf16x8v aq = *(const bf16x8v*)(qkv + (rowbase + i0 + lm)*576 + hh*32 + lh*8);

    f32x4v acc[22];
    #pragma unroll
    for(int jt=0;jt<22;jt++){
      bf16x8v bk = *(const bf16x8v*)(Kf + jt*512 + l*8);
      acc[jt] = mfma_bf16(aq, bk, z4);
    }

    int lia[4]; u32 lir[4];
    #pragma unroll
    for(int r=0;r<4;r++){
      int i = i0 + lh*4 + r; if(i>342) i=342;
      u32 t = lin_l[i];
      lia[r] = (int)(t & 0xffffu) + 1098;
      lir[r] = t >> 16;
    }
    #pragma unroll
    for(int jt=0;jt<22;jt++){
      u32 lj = lin_l[jt*16 + lm];
      int ljl = (int)(lj & 0xffffu); u32 ljr = lj >> 16;
      #pragma unroll
      for(int r=0;r<4;r++){
        int idx = lia[r] - ljl;
        acc[jt][r] = acc[jt][r] + bu(rpb_l[idx]) + ((lir[r]==ljr) ? 0.f : -100.f);
      }
    }

    float rinv[4];
    #pragma unroll
    for(int r=0;r<4;r++){
      float sm = 0.f;
      #pragma unroll
      for(int jt=0;jt<22;jt++){ float e = __expf(acc[jt][r]); acc[jt][r]=e; sm += e; }
      #pragma unroll
      for(int m=1;m<16;m<<=1) sm += __shfl_xor(sm, m);
      rinv[r] = 1.0f/sm;
    }

    f32x4v o0=z4, o1=z4;
    #pragma unroll
    for(int jt=0;jt<12;jt++){
      int jl = jt*16 + lm;
      #pragma unroll
      for(int r=0;r<4;r++) Pw[(lh*4+r)*200 + jl] = fb(acc[jt][r]);
    }
    #pragma unroll
    for(int ks=0;ks<6;ks++){
      bf16x8v ap = *(const bf16x8v*)(Pw + lm*200 + ks*32 + lh*8);
      bf16x8v b0 = *(const bf16x8v*)(Vt + lm*360 + ks*32 + lh*8);
      bf16x8v b1 = *(const bf16x8v*)(Vt + (16+lm)*360 + ks*32 + lh*8);
      o0 = mfma_bf16(ap, b0, o0);
      o1 = mfma_bf16(ap, b1, o1);
    }
    #pragma unroll
    for(int jt=12;jt<22;jt++){
      int jl = jt*16 + lm - 192;
      #pragma unroll
      for(int r=0;r<4;r++) Pw[(lh*4+r)*200 + jl] = fb(acc[jt][r]);
    }
    #pragma unroll
    for(int ks=0;ks<5;ks++){
      bf16x8v ap = *(const bf16x8v*)(Pw + lm*200 + ks*32 + lh*8);
      bf16x8v b0 = *(const bf16x8v*)(Vt + lm*360 + 192 + ks*32 + lh*8);
      bf16x8v b1 = *(const bf16x8v*)(Vt + (16+lm)*360 + 192 + ks*32 + lh*8);
      o0 = mfma_bf16(ap, b0, o0);
      o1 = mfma_bf16(ap, b1, o1);
    }

    #pragma unroll
    for(int r=0;r<4;r++){
      int i = i0 + lh*4 + r;
      if(i < 343){
        u16* po = out + (rowbase + i)*192 + hh*32;
        po[lm]    = fb(o0[r]*rinv[r]);
        po[16+lm] = fb(o1[r]*rinv[r]);
      }
    }
  }
}

// ---------------- depthwise 3x3x3 conv, x-blocked (standalone, for dw#2) ----------------
__global__ __launch_bounds__(256) void dw3v4(const u16* __restrict__ in, const float* __restrict__ kwT,
                                             const float* __restrict__ bias, u16* __restrict__ out){
  __shared__ float wls[5184];
  const int tid = threadIdx.x;
  for(int i=tid;i<5184;i+=256) wls[i] = kwT[i];
  __syncthreads();

  int gid = blockIdx.x*256 + tid;
  int c8 = gid % 24;
  int t  = gid / 24;
  int b  = t / 5488; int s = t - b*5488;
  int z  = s / 196;  int r = s - z*196;
  int y  = r / 7;    int x4 = r - y*7;
  int x0 = x4*4;

  float acc[4][8];
  {
    const float4* bp = (const float4*)(bias + c8*8);
    float4 b0 = bp[0], b1 = bp[1];
    #pragma unroll
    for(int xi=0;xi<4;xi++){
      acc[xi][0]=b0.x; acc[xi][1]=b0.y; acc[xi][2]=b0.z; acc[xi][3]=b0.w;
      acc[xi][4]=b1.x; acc[xi][5]=b1.y; acc[xi][6]=b1.z; acc[xi][7]=b1.w;
    }
  }

  #pragma unroll
  for(int dz=-1;dz<=1;dz++){
    int zz=z+dz; if((unsigned)zz>=28u) continue;
    #pragma unroll
    for(int dy=-1;dy<=1;dy++){
      int yy=y+dy; if((unsigned)yy>=28u) continue;
      const u16* rowp = in + (((long)b*LTOK + zz*784 + yy*28)*192) + c8*8;
      uint4 v[6];
      #pragma unroll
      for(int xc=0;xc<6;xc++){
        int xx = x0 + xc - 1;
        if((unsigned)xx < 28u) v[xc] = *(const uint4*)(rowp + (long)xx*192);
        else { v[xc].x=0; v[xc].y=0; v[xc].z=0; v[xc].w=0; }
      }
      #pragma unroll
      for(int dxi=0;dxi<3;dxi++){
        int tap = (dz+1)*9+(dy+1)*3+dxi;
        const float* wp = &wls[tap*192 + c8*8];
        float4 w0 = *(const float4*)wp;
        float4 w1 = *(const float4*)(wp+4);
        #pragma unroll
        for(int xi=0;xi<4;xi++){
          uint4 vv = v[xi+dxi];
          acc[xi][0] = fmaf(lo16(vv.x), w0.x, acc[xi][0]);
          acc[xi][1] = fmaf(hi16(vv.x), w0.y, acc[xi][1]);
          acc[xi][2] = fmaf(lo16(vv.y), w0.z, acc[xi][2]);
          acc[xi][3] = fmaf(hi16(vv.y), w0.w, acc[xi][3]);
          acc[xi][4] = fmaf(lo16(vv.z), w1.x, acc[xi][4]);
          acc[xi][5] = fmaf(hi16(vv.z), w1.y, acc[xi][5]);
          acc[xi][6] = fmaf(lo16(vv.w), w1.z, acc[xi][6]);
          acc[xi][7] = fmaf(hi16(vv.w), w1.w, acc[xi][7]);
        }
      }
    }
  }

  u16* op = out + (((long)b*LTOK + z*784 + y*28 + x0)*192) + c8*8;
  #pragma unroll
  for(int xi=0;xi<4;xi++){
    uint4 o;
    o.x = ((u32)fb(acc[xi][1])<<16) | fb(acc[xi][0]);
    o.y = ((u32)fb(acc[xi][3])<<16) | fb(acc[xi][2]);
    o.z = ((u32)fb(acc[xi][5])<<16) | fb(acc[xi][4]);
    o.w = ((u32)fb(acc[xi][7])<<16) | fb(acc[xi][6]);
    *(uint4*)(op + (long)xi*192) = o;
  }
}

// ---------------- final: x1 + lin + NCDHW-view gather of t2 -> f32 out (8 elem/thread) ----------------
__global__ __launch_bounds__(256) void final_add(const u16* __restrict__ x1, const u16* __restrict__ lin,
                                                 const u16* __restrict__ t2, float* __restrict__ out){
  int g8 = blockIdx.x*256 + threadIdx.x;
  int gid0 = g8*8;
  int b  = gid0 / 4214784;
  int gg = gid0 - b*4214784;
  int ch = gg / LTOK;
  int sp = gg - ch*LTOK;
  uint4 xa = *(const uint4*)(x1 + gid0);
  uint4 la = *(const uint4*)(lin + gid0);
  const u16* tp = t2 + ((long)b*LTOK + sp)*192 + ch;
  float4 o0, o1;
  o0.x = lo16(xa.x) + lo16(la.x) + bu(tp[0*192]);
  o0.y = hi16(xa.x) + hi16(la.x) + bu(tp[1*192]);
  o0.z = lo16(xa.y) + lo16(la.y) + bu(tp[2*192]);
  o0.w = hi16(xa.y) + hi16(la.y) + bu(tp[3*192]);
  o1.x = lo16(xa.z) + lo16(la.z) + bu(tp[4*192]);
  o1.y = hi16(xa.z) + hi16(la.z) + bu(tp[5*192]);
  o1.z = lo16(xa.w) + lo16(la.w) + bu(tp[6*192]);
  o1.w = hi16(xa.w) + hi16(la.w) + bu(tp[7*192]);
  *(float4*)(out + gid0)     = o0;
  *(float4*)(out + gid0 + 4) = o1;
}

extern "C" void kernel_launch(void* const* d_in, const int* in_sizes, int n_in,
                              void* d_out, int out_size, void* d_ws, size_t ws_size,
                              hipStream_t stream){
  const float* x      = (const float*)d_in[0];
  const float* n1g    = (const float*)d_in[2];
  const float* n1b    = (const float*)d_in[3];
  const float* qkv_w  = (const float*)d_in[4];
  const float* qkv_b  = (const float*)d_in[5];
  const float* rpb    = (const float*)d_in[6];
  const float* proj_w = (const float*)d_in[7];
  const float* proj_b = (const float*)d_in[8];
  const float* n2g    = (const float*)d_in[9];
  const float* n2b    = (const float*)d_in[10];
  const float* l1w    = (const float*)d_in[11];
  const float* l1b    = (const float*)d_in[12];
  const float* l2w    = (const float*)d_in[13];
  const float* l2b    = (const float*)d_in[14];
  const float* dw1k   = (const float*)d_in[15];
  const float* dw1b   = (const float*)d_in[16];
  const float* pw1k   = (const float*)d_in[17];
  const float* pw1b   = (const float*)d_in[18];
  const float* dw2k   = (const float*)d_in[19];
  const float* dw2b   = (const float*)d_in[20];
  const float* pw2k   = (const float*)d_in[21];
  const float* pw2b   = (const float*)d_in[22];

  const size_t FB = (size_t)ROWSZ * DIMC;
  u16* x1b   = (u16*)d_ws;
  u16* xmb   = x1b + FB;
  u16* attnb = xmb + FB;
  u16* qkvb  = attnb + FB;      // 3*FB
  u16* cb1   = qkvb;
  u16* cb2   = qkvb + FB;
  u16* linb  = attnb;
  u16* pk_qkv  = x1b + 6*FB;
  u16* pk_proj = pk_qkv  + 110592;
  u16* pk_l1   = pk_proj + 36864;
  u16* pk_l2   = pk_l1   + 147456;
  u16* pk_pw1  = pk_l2   + 147456;
  u16* pk_pw2  = pk_pw1  + 36864;
  float* kwT1  = (float*)(pk_pw2 + 36864);   // 5184 f32
  float* kwT2  = kwT1 + 5184;

  pack_w<0><<<432,256,0,stream>>>(qkv_w,  pk_qkv,  192, 576);
  pack_w<0><<<144,256,0,stream>>>(proj_w, pk_proj, 192, 192);
  pack_w<0><<<576,256,0,stream>>>(l1w,    pk_l1,   192, 768);
  pack_w<0><<<576,256,0,stream>>>(l2w,    pk_l2,   768, 192);
  pack_w<1><<<144,256,0,stream>>>(pw1k,   pk_pw1,  192, 192);
  pack_w<1><<<144,256,0,stream>>>(pw2k,   pk_pw2,  192, 192);
  pack_dwk<<<21,256,0,stream>>>(dw1k, dw2k, kwT1, kwT2);

  gemm_qkv_ln<<<ROWSZ/32,256,0,stream>>>(x, n1g, n1b, pk_qkv, qkv_b, qkvb);
  attn_mfma<<<128*6,256,0,stream>>>(qkvb, rpb, attnb);
  gemm_proj_ln<<<ROWSZ/32,256,0,stream>>>(attnb, pk_proj, proj_b, x, n2g, n2b, x1b, xmb);
  mlp_dw_fused<<<MLPBLK+1029,256,0,stream>>>(xmb, pk_l1, l1b, pk_l2, l2b, linb, kwT1, dw1b, cb1);
  gemm_mfma<192><<<ROWSZ/32,256,0,stream>>>(cb1, pk_pw1, pw1b, cb2);
  dw3v4<<<1029,256,0,stream>>>(cb2, kwT2, dw2b, cb1);
  gemm_mfma<192><<<ROWSZ/32,256,0,stream>>>(cb1, pk_pw2, pw2b, cb2);
  final_add<<<TOTE/2048,256,0,stream>>>(x1b, linb, cb2, (float*)d_out);
}

// Round 23
// 369.470 us; speedup vs baseline: 1.1568x; 1.1568x over previous
//
#include <hip/hip_runtime.h>

typedef unsigned short u16;
typedef unsigned int   u32;

#define DIMC 192
#define NWIN 343
#define LTOK 21952
#define ROWSZ 43904            // B * L rows
#define TOTE 8429568           // ROWSZ * DIMC
#define QSCALE 0.17677669529663689f
#define EPSF 1e-5f

typedef __attribute__((ext_vector_type(8))) short bf16x8v;
typedef __attribute__((ext_vector_type(4))) float f32x4v;

__device__ __forceinline__ float bu(u16 v){ union{u32 u; float f;} x; x.u = ((u32)v)<<16; return x.f; }
__device__ __forceinline__ float lo16(u32 p){ union{u32 u; float f;} x; x.u = p<<16; return x.f; }
__device__ __forceinline__ float hi16(u32 p){ union{u32 u; float f;} x; x.u = p & 0xffff0000u; return x.f; }
__device__ __forceinline__ u16 fb(float f){
  union{float ff; u32 u;} x; x.ff = f;
  u32 r = (x.u + 0x7fffu + ((x.u>>16)&1u)) >> 16;
  return (u16)r;
}
__device__ __forceinline__ float gelu_f(float x){ return 0.5f*x*(1.0f + erff(x*0.70710678118654752f)); }

__device__ __forceinline__ f32x4v mfma_bf16(bf16x8v a, bf16x8v b, f32x4v c){
  return __builtin_amdgcn_mfma_f32_16x16x32_bf16(a, b, c, 0, 0, 0);
}

// windowed-row -> (batch, token) bijection (shift -3 + partition).
__device__ __forceinline__ void row_to_token(int row, int& b, int& l){
  int bw = row / NWIN, n = row % NWIN;
  b = bw >> 6; int wi = bw & 63;
  int sd = (wi>>4)*7      + n/49;
  int sh = ((wi>>2)&3)*7  + (n/7)%7;
  int sw = (wi&3)*7       + n%7;
  int d = sd+3; if(d>=28) d-=28;
  int h = sh+3; if(h>=28) h-=28;
  int w = sw+3; if(w>=28) w-=28;
  l = d*784 + h*28 + w;
}

// ---------------- weight pre-pack into B-fragment order (bf16) ----------------
template<int TR>
__global__ __launch_bounds__(256) void pack_w(const float* __restrict__ W, u16* __restrict__ dst,
                                              int K, int N){
  int gid = blockIdx.x*256 + threadIdx.x;
  if(gid >= K*N) return;
  int k = gid / N, n = gid - k*N;
  float v = TR ? W[(long)n*K + k] : W[(long)k*N + n];
  int nt = n >> 4, ks = k >> 5;
  int l  = (((k>>3)&3)<<4) | (n&15);
  int j  = k & 7;
  int KS = K >> 5;
  dst[((((nt*KS + ks)<<6) + l)<<3) + j] = fb(v);
}

// ---------------- depthwise weight transpose: [192][27] -> [27][192] ----------------
__global__ __launch_bounds__(256) void pack_dwk(const float* __restrict__ k1, const float* __restrict__ k2,
                                                float* __restrict__ d1, float* __restrict__ d2){
  int gid = blockIdx.x*256 + threadIdx.x;
  if(gid < 5184){
    int tap = gid/192, c = gid - tap*192;
    d1[gid] = k1[c*27 + tap];
    d2[gid] = k2[c*27 + tap];
  }
}

// ---------------- fused LN1 + QKV GEMM (q pre-scaled by QSCALE) ----------------
__global__ __launch_bounds__(256) void gemm_qkv_ln(const float* __restrict__ x, const float* __restrict__ g,
                                                   const float* __restrict__ bb, const u16* __restrict__ Wp,
                                                   const float* __restrict__ bias, u16* __restrict__ out){
  __shared__ float Xs[32*192];
  __shared__ u16 As[32*192];
  __shared__ long tb_l[32];
  const int tid = threadIdx.x;
  const int w = tid>>6, l = tid&63;
  const int lm = l&15, lh = l>>4;
  const long row0 = (long)blockIdx.x*32;

  if(tid < 32){
    int b_, lt; row_to_token((int)(row0+tid), b_, lt);
    tb_l[tid] = ((long)b_*LTOK + lt)*DIMC;
  }
  __syncthreads();

  #pragma unroll
  for(int c=0;c<24;c++){
    int idx = tid + c*256;
    int row = idx/192, col = idx - row*192;
    Xs[idx] = x[tb_l[row] + col];
  }
  __syncthreads();

  for(int rr=0;rr<8;rr++){
    int row = w*8 + rr;
    const float* pr = &Xs[row*192];
    float v0 = pr[l], v1 = pr[l+64], v2 = pr[l+128];
    float s = v0+v1+v2;
    #pragma unroll
    for(int m=1;m<64;m<<=1) s += __shfl_xor(s,m);
    float mean = s*(1.f/192.f);
    float d0=v0-mean, d1=v1-mean, d2=v2-mean;
    float q = d0*d0+d1*d1+d2*d2;
    #pragma unroll
    for(int m=1;m<64;m<<=1) q += __shfl_xor(q,m);
    float rstd = rsqrtf(q*(1.f/192.f)+EPSF);
    *(u16*)((char*)As + ((row*384 + 2*l)       ^ ((row&7)<<4))) = fb(d0*rstd*g[l]     + bb[l]);
    *(u16*)((char*)As + ((row*384 + 2*(l+64))  ^ ((row&7)<<4))) = fb(d1*rstd*g[l+64]  + bb[l+64]);
    *(u16*)((char*)As + ((row*384 + 2*(l+128)) ^ ((row&7)<<4))) = fb(d2*rstd*g[l+128] + bb[l+128]);
  }
  __syncthreads();

  f32x4v acc[9][2];
  const f32x4v z4 = {0.f,0.f,0.f,0.f};
  #pragma unroll
  for(int i=0;i<9;i++){ acc[i][0]=z4; acc[i][1]=z4; }

  #pragma unroll
  for(int ks=0;ks<6;ks++){
    bf16x8v a[2];
    #pragma unroll
    for(int mt=0;mt<2;mt++){
      int row = mt*16 + lm;
      int byte = (row*384 + ks*64 + lh*16) ^ ((row&7)<<4);
      a[mt] = *(const bf16x8v*)((const char*)As + byte);
    }
    #pragma unroll
    for(int i=0;i<9;i++){
      int nt = w*9 + i;
      bf16x8v b = *(const bf16x8v*)(Wp + ((((nt*6 + ks)<<6) + l)<<3));
      acc[i][0] = mfma_bf16(a[0], b, acc[i][0]);
      acc[i][1] = mfma_bf16(a[1], b, acc[i][1]);
    }
  }

  #pragma unroll
  for(int i=0;i<9;i++){
    int n = (w*9 + i)*16 + lm;
    float bv = bias[n];
    #pragma unroll
    for(int mt=0;mt<2;mt++){
      #pragma unroll
      for(int r=0;r<4;r++){
        long mrow = row0 + mt*16 + lh*4 + r;
        float v = acc[i][mt][r] + bv;
        if(n < 192) v *= QSCALE;
        out[mrow*576 + n] = fb(v);
      }
    }
  }
}

// ---------------- fused proj GEMM + residual + LN2 ----------------
__global__ __launch_bounds__(256) void gemm_proj_ln(const u16* __restrict__ A, const u16* __restrict__ Wp,
                                                    const float* __restrict__ bias, const float* __restrict__ resid,
                                                    const float* __restrict__ g, const float* __restrict__ bb,
                                                    u16* __restrict__ x1o, u16* __restrict__ xmo){
  __shared__ u16 As[32*192];
  __shared__ float Vs2[32*200];
  __shared__ long tb_l[32];
  const int tid = threadIdx.x;
  const int w = tid>>6, l = tid&63;
  const int lm = l&15, lh = l>>4;
  const long row0 = (long)blockIdx.x*32;

  if(tid < 32){
    int b_, lt; row_to_token((int)(row0+tid), b_, lt);
    tb_l[tid] = ((long)b_*LTOK + lt)*DIMC;
  }
  {
    const uint4* src = (const uint4*)(A + row0*192);
    #pragma unroll
    for(int c=0;c<3;c++){
      int cz = tid + c*256;
      int row = cz/24;
      int byte = (cz*16) ^ ((row&7)<<4);
      *(uint4*)((char*)As + byte) = src[cz];
    }
  }
  __syncthreads();

  f32x4v acc[3][2];
  const f32x4v z4 = {0.f,0.f,0.f,0.f};
  #pragma unroll
  for(int i=0;i<3;i++){ acc[i][0]=z4; acc[i][1]=z4; }

  #pragma unroll
  for(int ks=0;ks<6;ks++){
    bf16x8v a[2];
    #pragma unroll
    for(int mt=0;mt<2;mt++){
      int row = mt*16 + lm;
      int byte = (row*384 + ks*64 + lh*16) ^ ((row&7)<<4);
      a[mt] = *(const bf16x8v*)((const char*)As + byte);
    }
    #pragma unroll
    for(int i=0;i<3;i++){
      int nt = w*3 + i;
      bf16x8v b = *(const bf16x8v*)(Wp + ((((nt*6 + ks)<<6) + l)<<3));
      acc[i][0] = mfma_bf16(a[0], b, acc[i][0]);
      acc[i][1] = mfma_bf16(a[1], b, acc[i][1]);
    }
  }

  #pragma unroll
  for(int i=0;i<3;i++){
    int n = (w*3 + i)*16 + lm;
    float bv = bias[n];
    #pragma unroll
    for(int mt=0;mt<2;mt++){
      #pragma unroll
      for(int r=0;r<4;r++){
        int row = mt*16 + lh*4 + r;
        Vs2[row*200 + n] = acc[i][mt][r] + bv + resid[tb_l[row] + n];
      }
    }
  }
  __syncthreads();

  for(int rr=0;rr<8;rr++){
    int row = w*8 + rr;
    long tb = tb_l[row];
    const float* pr = &Vs2[row*200];
    float v0 = pr[l], v1 = pr[l+64], v2 = pr[l+128];
    float s = v0+v1+v2;
    #pragma unroll
    for(int m=1;m<64;m<<=1) s += __shfl_xor(s,m);
    float mean = s*(1.f/192.f);
    float d0=v0-mean, d1=v1-mean, d2=v2-mean;
    float q = d0*d0+d1*d1+d2*d2;
    #pragma unroll
    for(int m=1;m<64;m<<=1) q += __shfl_xor(q,m);
    float rstd = rsqrtf(q*(1.f/192.f)+EPSF);
    x1o[tb+l]     = fb(v0);
    x1o[tb+l+64]  = fb(v1);
    x1o[tb+l+128] = fb(v2);
    xmo[tb+l]     = fb(d0*rstd*g[l]     + bb[l]);
    xmo[tb+l+64]  = fb(d1*rstd*g[l+64]  + bb[l+64]);
    xmo[tb+l+128] = fb(d2*rstd*g[l+128] + bb[l+128]);
  }
}

// ---------------- MFMA GEMM (pointwise convs): 32 rows/block, K=192 ----------------
template<int NTOT>
__global__ __launch_bounds__(256) void gemm_mfma(const u16* __restrict__ A, const u16* __restrict__ Wp,
                                                 const float* __restrict__ bias, u16* __restrict__ out){
  constexpr int KS  = 6;
  constexpr int NPW = NTOT/64;
  __shared__ u16 As[32*192];
  const int tid = threadIdx.x;
  const int w = tid>>6, l = tid&63;
  const int lm = l&15, lh = l>>4;
  const long row0 = (long)blockIdx.x*32;

  {
    const uint4* src = (const uint4*)(A + row0*192);
    #pragma unroll
    for(int c=0;c<3;c++){
      int cz = tid + c*256;
      int row = cz/24;
      int byte = (cz*16) ^ ((row&7)<<4);
      *(uint4*)((char*)As + byte) = src[cz];
    }
  }
  __syncthreads();

  f32x4v acc[NPW][2];
  const f32x4v z4 = {0.f,0.f,0.f,0.f};
  #pragma unroll
  for(int i=0;i<NPW;i++){ acc[i][0]=z4; acc[i][1]=z4; }

  #pragma unroll
  for(int ks=0;ks<KS;ks++){
    bf16x8v a[2];
    #pragma unroll
    for(int mt=0;mt<2;mt++){
      int row = mt*16 + lm;
      int byte = (row*384 + ks*64 + lh*16) ^ ((row&7)<<4);
      a[mt] = *(const bf16x8v*)((const char*)As + byte);
    }
    #pragma unroll
    for(int i=0;i<NPW;i++){
      int nt = w*NPW + i;
      bf16x8v b = *(const bf16x8v*)(Wp + ((((nt*KS + ks)<<6) + l)<<3));
      acc[i][0] = mfma_bf16(a[0], b, acc[i][0]);
      acc[i][1] = mfma_bf16(a[1], b, acc[i][1]);
    }
  }

  #pragma unroll
  for(int i=0;i<NPW;i++){
    int n = (w*NPW + i)*16 + lm;
    float bv = bias[n];
    #pragma unroll
    for(int mt=0;mt<2;mt++){
      #pragma unroll
      for(int r=0;r<4;r++){
        long mrow = row0 + mt*16 + lh*4 + r;
        out[mrow*NTOT + n] = fb(acc[i][mt][r] + bv);
      }
    }
  }
}

// ---------------- fused MLP via MFMA (r13-proven, erff GELU): h in 48 KB LDS ----------------
__global__ __launch_bounds__(256) void mlp_mfma(const u16* __restrict__ xm, const u16* __restrict__ Wp1,
                                                const float* __restrict__ b1, const u16* __restrict__ Wp2,
                                                const float* __restrict__ b2, u16* __restrict__ out){
  __shared__ u16 As[32*192];
  __shared__ u16 Hs[32*768];
  const int tid = threadIdx.x;
  const int w = tid>>6, l = tid&63;
  const int lm = l&15, lh = l>>4;
  const long row0 = (long)blockIdx.x*32;

  {
    const uint4* src = (const uint4*)(xm + row0*192);
    #pragma unroll
    for(int c=0;c<3;c++){
      int cz = tid + c*256;
      int row = cz/24;
      int byte = (cz*16) ^ ((row&7)<<4);
      *(uint4*)((char*)As + byte) = src[cz];
    }
  }
  __syncthreads();

  const f32x4v z4 = {0.f,0.f,0.f,0.f};
  f32x4v acc1[12][2];
  #pragma unroll
  for(int i=0;i<12;i++){ acc1[i][0]=z4; acc1[i][1]=z4; }

  #pragma unroll
  for(int ks=0;ks<6;ks++){
    bf16x8v a[2];
    #pragma unroll
    for(int mt=0;mt<2;mt++){
      int row = mt*16 + lm;
      int byte = (row*384 + ks*64 + lh*16) ^ ((row&7)<<4);
      a[mt] = *(const bf16x8v*)((const char*)As + byte);
    }
    #pragma unroll
    for(int i=0;i<12;i++){
      int nt = w*12 + i;
      bf16x8v b = *(const bf16x8v*)(Wp1 + ((((nt*6 + ks)<<6) + l)<<3));
      acc1[i][0] = mfma_bf16(a[0], b, acc1[i][0]);
      acc1[i][1] = mfma_bf16(a[1], b, acc1[i][1]);
    }
  }

  #pragma unroll
  for(int i=0;i<12;i++){
    int n = (w*12 + i)*16 + lm;
    float bv = b1[n];
    #pragma unroll
    for(int mt=0;mt<2;mt++){
      #pragma unroll
      for(int r=0;r<4;r++){
        int mrow = mt*16 + lh*4 + r;
        float h = gelu_f(acc1[i][mt][r] + bv);
        int byte = (mrow*1536 + n*2) ^ ((mrow&7)<<4);
        *(u16*)((char*)Hs + byte) = fb(h);
      }
    }
  }
  __syncthreads();

  f32x4v acc2[3][2];
  #pragma unroll
  for(int i=0;i<3;i++){ acc2[i][0]=z4; acc2[i][1]=z4; }

  #pragma unroll 4
  for(int ks=0;ks<24;ks++){
    bf16x8v a[2];
    #pragma unroll
    for(int mt=0;mt<2;mt++){
      int row = mt*16 + lm;
      int byte = (row*1536 + ks*64 + lh*16) ^ ((row&7)<<4);
      a[mt] = *(const bf16x8v*)((const char*)Hs + byte);
    }
    #pragma unroll
    for(int i=0;i<3;i++){
      int nt = w*3 + i;
      bf16x8v b = *(const bf16x8v*)(Wp2 + ((((nt*24 + ks)<<6) + l)<<3));
      acc2[i][0] = mfma_bf16(a[0], b, acc2[i][0]);
      acc2[i][1] = mfma_bf16(a[1], b, acc2[i][1]);
    }
  }

  #pragma unroll
  for(int i=0;i<3;i++){
    int n = (w*3 + i)*16 + lm;
    float bv = b2[n];
    #pragma unroll
    for(int mt=0;mt<2;mt++){
      #pragma unroll
      for(int r=0;r<4;r++){
        long mrow = row0 + mt*16 + lh*4 + r;
        out[mrow*192 + n] = fb(acc2[i][mt][r] + bv);
      }
    }
  }
}

// ---------------- MFMA attention v3' ----------------
__global__ __launch_bounds__(256) void attn_mfma(const u16* __restrict__ qkv, const float* __restrict__ rpb,
                                                 u16* __restrict__ out){
  __shared__ u16 Kf[22*512];
  __shared__ u16 Vt[32*360];
  __shared__ u16 Ps[4][16*200];
  __shared__ u16 rpb_l[2198];
  __shared__ u32 lin_l[352];

  const int tid = threadIdx.x;
  const int bw = blockIdx.x / 6, hh = blockIdx.x % 6;
  const int wi = bw & 63;
  const long rowbase = (long)bw*NWIN;

  for(int i=tid;i<2197;i+=256) rpb_l[i] = fb(rpb[i*6+hh]);
  for(int i2=tid;i2<352;i2+=256){
    u32 v = 0x7FFF0000u;
    if(i2 < 343){
      int jz = i2/49, jr = i2-jz*49, jy = jr/7, jx = jr-jy*7;
      int sd = (wi>>4)*7 + jz, sh2 = ((wi>>2)&3)*7 + jy, sw = (wi&3)*7 + jx;
      int rd = sd<21?0:(sd<25?1:2);
      int rh = sh2<21?0:(sh2<25?1:2);
      int rw = sw<21?0:(sw<25?1:2);
      v = (u32)(jz*169 + jy*13 + jx) | ((u32)(rd*9+rh*3+rw)<<16);
    }
    lin_l[i2] = v;
  }
  for(int p2=tid;p2<288;p2+=256){
    int d = p2/9, j = 343 + p2%9; Vt[d*360 + j] = 0;
  }
  ((u32*)Kf)[21*256 + tid] = 0;
  __syncthreads();

  for(int p = tid; p < 343*16; p += 256){
    int j = p >> 4, dp = p & 15;
    const u32* src = (const u32*)(qkv + (rowbase + j)*576 + hh*32) + dp;
    u32 kk = src[96];
    u32 vv = src[192];
    ((u32*)Kf)[(j>>4)*256 + ((dp>>2)*16 + (j&15))*4 + (dp&3)] = kk;
    Vt[(dp*2)*360 + j]   = (u16)(vv & 0xffffu);
    Vt[(dp*2+1)*360 + j] = (u16)(vv >> 16);
  }
  __syncthreads();

  const int w = tid>>6, l = tid&63;
  const int lm = l&15, lh = l>>4;
  u16* Pw = Ps[w];
  const f32x4v z4 = {0.f,0.f,0.f,0.f};

  for(int it = w; it < 22; it += 4){
    const int i0 = it*16;
    bf16x8v aq = *(const bf16x8v*)(qkv + (rowbase + i0 + lm)*576 + hh*32 + lh*8);

    f32x4v acc[22];
    #pragma unroll
    for(int jt=0;jt<22;jt++){
      bf16x8v bk = *(const bf16x8v*)(Kf + jt*512 + l*8);
      acc[jt] = mfma_bf16(aq, bk, z4);
    }

    int lia[4]; u32 lir[4];
    #pragma unroll
    for(int r=0;r<4;r++){
      int i = i0 + lh*4 + r; if(i>342) i=342;
      u32 t = lin_l[i];
      lia[r] = (int)(t & 0xffffu) + 1098;
      lir[r] = t >> 16;
    }
    #pragma unroll
    for(int jt=0;jt<22;jt++){
      u32 lj = lin_l[jt*16 + lm];
      int ljl = (int)(lj & 0xffffu); u32 ljr = lj >> 16;
      #pragma unroll
      for(int r=0;r<4;r++){
        int idx = lia[r] - ljl;
        acc[jt][r] = acc[jt][r] + bu(rpb_l[idx]) + ((lir[r]==ljr) ? 0.f : -100.f);
      }
    }

    float rinv[4];
    #pragma unroll
    for(int r=0;r<4;r++){
      float sm = 0.f;
      #pragma unroll
      for(int jt=0;jt<22;jt++){ float e = __expf(acc[jt][r]); acc[jt][r]=e; sm += e; }
      #pragma unroll
      for(int m=1;m<16;m<<=1) sm += __shfl_xor(sm, m);
      rinv[r] = 1.0f/sm;
    }

    f32x4v o0=z4, o1=z4;
    #pragma unroll
    for(int jt=0;jt<12;jt++){
      int jl = jt*16 + lm;
      #pragma unroll
      for(int r=0;r<4;r++) Pw[(lh*4+r)*200 + jl] = fb(acc[jt][r]);
    }
    #pragma unroll
    for(int ks=0;ks<6;ks++){
      bf16x8v ap = *(const bf16x8v*)(Pw + lm*200 + ks*32 + lh*8);
      bf16x8v b0 = *(const bf16x8v*)(Vt + lm*360 + ks*32 + lh*8);
      bf16x8v b1 = *(const bf16x8v*)(Vt + (16+lm)*360 + ks*32 + lh*8);
      o0 = mfma_bf16(ap, b0, o0);
      o1 = mfma_bf16(ap, b1, o1);
    }
    #pragma unroll
    for(int jt=12;jt<22;jt++){
      int jl = jt*16 + lm - 192;
      #pragma unroll
      for(int r=0;r<4;r++) Pw[(lh*4+r)*200 + jl] = fb(acc[jt][r]);
    }
    #pragma unroll
    for(int ks=0;ks<5;ks++){
      bf16x8v ap = *(const bf16x8v*)(Pw + lm*200 + ks*32 + lh*8);
      bf16x8v b0 = *(const bf16x8v*)(Vt + lm*360 + 192 + ks*32 + lh*8);
      bf16x8v b1 = *(const bf16x8v*)(Vt + (16+lm)*360 + 192 + ks*32 + lh*8);
      o0 = mfma_bf16(ap, b0, o0);
      o1 = mfma_bf16(ap, b1, o1);
    }

    #pragma unroll
    for(int r=0;r<4;r++){
      int i = i0 + lh*4 + r;
      if(i < 343){
        u16* po = out + (rowbase + i)*192 + hh*32;
        po[lm]    = fb(o0[r]*rinv[r]);
        po[16+lm] = fb(o1[r]*rinv[r]);
      }
    }
  }
}

// ---------------- depthwise 3x3x3 conv, x-blocked: 4 outputs x 8 ch per thread ----------------
__global__ __launch_bounds__(256) void dw3v4(const u16* __restrict__ in, const float* __restrict__ kwT,
                                             const float* __restrict__ bias, u16* __restrict__ out){
  __shared__ float wls[5184];
  const int tid = threadIdx.x;
  for(int i=tid;i<5184;i+=256) wls[i] = kwT[i];
  __syncthreads();

  int gid = blockIdx.x*256 + tid;
  int c8 = gid % 24;
  int t  = gid / 24;
  int b  = t / 5488; int s = t - b*5488;
  int z  = s / 196;  int r = s - z*196;
  int y  = r / 7;    int x4 = r - y*7;
  int x0 = x4*4;

  float acc[4][8];
  {
    const float4* bp = (const float4*)(bias + c8*8);
    float4 b0 = bp[0], b1 = bp[1];
    #pragma unroll
    for(int xi=0;xi<4;xi++){
      acc[xi][0]=b0.x; acc[xi][1]=b0.y; acc[xi][2]=b0.z; acc[xi][3]=b0.w;
      acc[xi][4]=b1.x; acc[xi][5]=b1.y; acc[xi][6]=b1.z; acc[xi][7]=b1.w;
    }
  }

  #pragma unroll
  for(int dz=-1;dz<=1;dz++){
    int zz=z+dz; if((unsigned)zz>=28u) continue;
    #pragma unroll
    for(int dy=-1;dy<=1;dy++){
      int yy=y+dy; if((unsigned)yy>=28u) continue;
      const u16* rowp = in + (((long)b*LTOK + zz*784 + yy*28)*192) + c8*8;
      uint4 v[6];
      #pragma unroll
      for(int xc=0;xc<6;xc++){
        int xx = x0 + xc - 1;
        if((unsigned)xx < 28u) v[xc] = *(const uint4*)(rowp + (long)xx*192);
        else { v[xc].x=0; v[xc].y=0; v[xc].z=0; v[xc].w=0; }
      }
      #pragma unroll
      for(int dxi=0;dxi<3;dxi++){
        int tap = (dz+1)*9+(dy+1)*3+dxi;
        const float* wp = &wls[tap*192 + c8*8];
        float4 w0 = *(const float4*)wp;
        float4 w1 = *(const float4*)(wp+4);
        #pragma unroll
        for(int xi=0;xi<4;xi++){
          uint4 vv = v[xi+dxi];
          acc[xi][0] = fmaf(lo16(vv.x), w0.x, acc[xi][0]);
          acc[xi][1] = fmaf(hi16(vv.x), w0.y, acc[xi][1]);
          acc[xi][2] = fmaf(lo16(vv.y), w0.z, acc[xi][2]);
          acc[xi][3] = fmaf(hi16(vv.y), w0.w, acc[xi][3]);
          acc[xi][4] = fmaf(lo16(vv.z), w1.x, acc[xi][4]);
          acc[xi][5] = fmaf(hi16(vv.z), w1.y, acc[xi][5]);
          acc[xi][6] = fmaf(lo16(vv.w), w1.z, acc[xi][6]);
          acc[xi][7] = fmaf(hi16(vv.w), w1.w, acc[xi][7]);
        }
      }
    }
  }

  u16* op = out + (((long)b*LTOK + z*784 + y*28 + x0)*192) + c8*8;
  #pragma unroll
  for(int xi=0;xi<4;xi++){
    uint4 o;
    o.x = ((u32)fb(acc[xi][1])<<16) | fb(acc[xi][0]);
    o.y = ((u32)fb(acc[xi][3])<<16) | fb(acc[xi][2]);
    o.z = ((u32)fb(acc[xi][5])<<16) | fb(acc[xi][4]);
    o.w = ((u32)fb(acc[xi][7])<<16) | fb(acc[xi][6]);
    *(uint4*)(op + (long)xi*192) = o;
  }
}

// ---------------- final: x1 + lin + NCDHW-view gather of t2 -> f32 out (8 elem/thread) ----------------
__global__ __launch_bounds__(256) void final_add(const u16* __restrict__ x1, const u16* __restrict__ lin,
                                                 const u16* __restrict__ t2, float* __restrict__ out){
  int g8 = blockIdx.x*256 + threadIdx.x;
  int gid0 = g8*8;
  int b  = gid0 / 4214784;
  int gg = gid0 - b*4214784;
  int ch = gg / LTOK;
  int sp = gg - ch*LTOK;
  uint4 xa = *(const uint4*)(x1 + gid0);
  uint4 la = *(const uint4*)(lin + gid0);
  const u16* tp = t2 + ((long)b*LTOK + sp)*192 + ch;
  float4 o0, o1;
  o0.x = lo16(xa.x) + lo16(la.x) + bu(tp[0*192]);
  o0.y = hi16(xa.x) + hi16(la.x) + bu(tp[1*192]);
  o0.z = lo16(xa.y) + lo16(la.y) + bu(tp[2*192]);
  o0.w = hi16(xa.y) + hi16(la.y) + bu(tp[3*192]);
  o1.x = lo16(xa.z) + lo16(la.z) + bu(tp[4*192]);
  o1.y = hi16(xa.z) + hi16(la.z) + bu(tp[5*192]);
  o1.z = lo16(xa.w) + lo16(la.w) + bu(tp[6*192]);
  o1.w = hi16(xa.w) + hi16(la.w) + bu(tp[7*192]);
  *(float4*)(out + gid0)     = o0;
  *(float4*)(out + gid0 + 4) = o1;
}

extern "C" void kernel_launch(void* const* d_in, const int* in_sizes, int n_in,
                              void* d_out, int out_size, void* d_ws, size_t ws_size,
                              hipStream_t stream){
  const float* x      = (const float*)d_in[0];
  const float* n1g    = (const float*)d_in[2];
  const float* n1b    = (const float*)d_in[3];
  const float* qkv_w  = (const float*)d_in[4];
  const float* qkv_b  = (const float*)d_in[5];
  const float* rpb    = (const float*)d_in[6];
  const float* proj_w = (const float*)d_in[7];
  const float* proj_b = (const float*)d_in[8];
  const float* n2g    = (const float*)d_in[9];
  const float* n2b    = (const float*)d_in[10];
  const float* l1w    = (const float*)d_in[11];
  const float* l1b    = (const float*)d_in[12];
  const float* l2w    = (const float*)d_in[13];
  const float* l2b    = (const float*)d_in[14];
  const float* dw1k   = (const float*)d_in[15];
  const float* dw1b   = (const float*)d_in[16];
  const float* pw1k   = (const float*)d_in[17];
  const float* pw1b   = (const float*)d_in[18];
  const float* dw2k   = (const float*)d_in[19];
  const float* dw2b   = (const float*)d_in[20];
  const float* pw2k   = (const float*)d_in[21];
  const float* pw2b   = (const float*)d_in[22];

  const size_t FB = (size_t)ROWSZ * DIMC;
  u16* x1b   = (u16*)d_ws;
  u16* xmb   = x1b + FB;
  u16* attnb = xmb + FB;
  u16* qkvb  = attnb + FB;      // 3*FB
  u16* cb1   = qkvb;
  u16* cb2   = qkvb + FB;
  u16* linb  = attnb;
  u16* pk_qkv  = x1b + 6*FB;
  u16* pk_proj = pk_qkv  + 110592;
  u16* pk_l1   = pk_proj + 36864;
  u16* pk_l2   = pk_l1   + 147456;
  u16* pk_pw1  = pk_l2   + 147456;
  u16* pk_pw2  = pk_pw1  + 36864;
  float* kwT1  = (float*)(pk_pw2 + 36864);   // 5184 f32
  float* kwT2  = kwT1 + 5184;

  pack_w<0><<<432,256,0,stream>>>(qkv_w,  pk_qkv,  192, 576);
  pack_w<0><<<144,256,0,stream>>>(proj_w, pk_proj, 192, 192);
  pack_w<0><<<576,256,0,stream>>>(l1w,    pk_l1,   192, 768);
  pack_w<0><<<576,256,0,stream>>>(l2w,    pk_l2,   768, 192);
  pack_w<1><<<144,256,0,stream>>>(pw1k,   pk_pw1,  192, 192);
  pack_w<1><<<144,256,0,stream>>>(pw2k,   pk_pw2,  192, 192);
  pack_dwk<<<21,256,0,stream>>>(dw1k, dw2k, kwT1, kwT2);

  gemm_qkv_ln<<<ROWSZ/32,256,0,stream>>>(x, n1g, n1b, pk_qkv, qkv_b, qkvb);
  attn_mfma<<<128*6,256,0,stream>>>(qkvb, rpb, attnb);
  gemm_proj_ln<<<ROWSZ/32,256,0,stream>>>(attnb, pk_proj, proj_b, x, n2g, n2b, x1b, xmb);
  mlp_mfma<<<ROWSZ/32,256,0,stream>>>(xmb, pk_l1, l1b, pk_l2, l2b, linb);
  dw3v4<<<1029,256,0,stream>>>(xmb, kwT1, dw1b, cb1);
  gemm_mfma<192><<<ROWSZ/32,256,0,stream>>>(cb1, pk_pw1, pw1b, cb2);
  dw3v4<<<1029,256,0,stream>>>(cb2, kwT2, dw2b, cb1);
  gemm_mfma<192><<<ROWSZ/32,256,0,stream>>>(cb1, pk_pw2, pw2b, cb2);
  final_add<<<TOTE/2048,256,0,stream>>>(x1b, linb, cb2, (float*)d_out);
}

// Round 24
// 368.989 us; speedup vs baseline: 1.1583x; 1.0013x over previous
//
#include <hip/hip_runtime.h>

typedef unsigned short u16;
typedef unsigned int   u32;

#define DIMC 192
#define NWIN 343
#define LTOK 21952
#define ROWSZ 43904            // B * L rows
#define TOTE 8429568           // ROWSZ * DIMC
#define QSCALE 0.17677669529663689f
#define EPSF 1e-5f

typedef __attribute__((ext_vector_type(8))) short bf16x8v;
typedef __attribute__((ext_vector_type(4))) float f32x4v;

__device__ __forceinline__ float bu(u16 v){ union{u32 u; float f;} x; x.u = ((u32)v)<<16; return x.f; }
__device__ __forceinline__ float lo16(u32 p){ union{u32 u; float f;} x; x.u = p<<16; return x.f; }
__device__ __forceinline__ float hi16(u32 p){ union{u32 u; float f;} x; x.u = p & 0xffff0000u; return x.f; }
__device__ __forceinline__ u16 fb(float f){
  union{float ff; u32 u;} x; x.ff = f;
  u32 r = (x.u + 0x7fffu + ((x.u>>16)&1u)) >> 16;
  return (u16)r;
}
__device__ __forceinline__ float gelu_f(float x){ return 0.5f*x*(1.0f + erff(x*0.70710678118654752f)); }

__device__ __forceinline__ f32x4v mfma_bf16(bf16x8v a, bf16x8v b, f32x4v c){
  return __builtin_amdgcn_mfma_f32_16x16x32_bf16(a, b, c, 0, 0, 0);
}

// windowed-row -> (batch, token) bijection (shift -3 + partition).
__device__ __forceinline__ void row_to_token(int row, int& b, int& l){
  int bw = row / NWIN, n = row % NWIN;
  b = bw >> 6; int wi = bw & 63;
  int sd = (wi>>4)*7      + n/49;
  int sh = ((wi>>2)&3)*7  + (n/7)%7;
  int sw = (wi&3)*7       + n%7;
  int d = sd+3; if(d>=28) d-=28;
  int h = sh+3; if(h>=28) h-=28;
  int w = sw+3; if(w>=28) w-=28;
  l = d*784 + h*28 + w;
}

// ---------------- weight pre-pack into B-fragment order (bf16) ----------------
template<int TR>
__global__ __launch_bounds__(256) void pack_w(const float* __restrict__ W, u16* __restrict__ dst,
                                              int K, int N){
  int gid = blockIdx.x*256 + threadIdx.x;
  if(gid >= K*N) return;
  int k = gid / N, n = gid - k*N;
  float v = TR ? W[(long)n*K + k] : W[(long)k*N + n];
  int nt = n >> 4, ks = k >> 5;
  int l  = (((k>>3)&3)<<4) | (n&15);
  int j  = k & 7;
  int KS = K >> 5;
  dst[((((nt*KS + ks)<<6) + l)<<3) + j] = fb(v);
}

// ---------------- depthwise weight transpose: [192][27] -> [27][192] ----------------
__global__ __launch_bounds__(256) void pack_dwk(const float* __restrict__ k1, const float* __restrict__ k2,
                                                float* __restrict__ d1, float* __restrict__ d2){
  int gid = blockIdx.x*256 + threadIdx.x;
  if(gid < 5184){
    int tap = gid/192, c = gid - tap*192;
    d1[gid] = k1[c*27 + tap];
    d2[gid] = k2[c*27 + tap];
  }
}

// ---------------- fused LN1 + QKV GEMM (q pre-scaled by QSCALE) ----------------
__global__ __launch_bounds__(256) void gemm_qkv_ln(const float* __restrict__ x, const float* __restrict__ g,
                                                   const float* __restrict__ bb, const u16* __restrict__ Wp,
                                                   const float* __restrict__ bias, u16* __restrict__ out){
  __shared__ float Xs[32*192];
  __shared__ u16 As[32*192];
  __shared__ long tb_l[32];
  const int tid = threadIdx.x;
  const int w = tid>>6, l = tid&63;
  const int lm = l&15, lh = l>>4;
  const long row0 = (long)blockIdx.x*32;

  if(tid < 32){
    int b_, lt; row_to_token((int)(row0+tid), b_, lt);
    tb_l[tid] = ((long)b_*LTOK + lt)*DIMC;
  }
  __syncthreads();

  #pragma unroll
  for(int c=0;c<24;c++){
    int idx = tid + c*256;
    int row = idx/192, col = idx - row*192;
    Xs[idx] = x[tb_l[row] + col];
  }
  __syncthreads();

  for(int rr=0;rr<8;rr++){
    int row = w*8 + rr;
    const float* pr = &Xs[row*192];
    float v0 = pr[l], v1 = pr[l+64], v2 = pr[l+128];
    float s = v0+v1+v2;
    #pragma unroll
    for(int m=1;m<64;m<<=1) s += __shfl_xor(s,m);
    float mean = s*(1.f/192.f);
    float d0=v0-mean, d1=v1-mean, d2=v2-mean;
    float q = d0*d0+d1*d1+d2*d2;
    #pragma unroll
    for(int m=1;m<64;m<<=1) q += __shfl_xor(q,m);
    float rstd = rsqrtf(q*(1.f/192.f)+EPSF);
    *(u16*)((char*)As + ((row*384 + 2*l)       ^ ((row&7)<<4))) = fb(d0*rstd*g[l]     + bb[l]);
    *(u16*)((char*)As + ((row*384 + 2*(l+64))  ^ ((row&7)<<4))) = fb(d1*rstd*g[l+64]  + bb[l+64]);
    *(u16*)((char*)As + ((row*384 + 2*(l+128)) ^ ((row&7)<<4))) = fb(d2*rstd*g[l+128] + bb[l+128]);
  }
  __syncthreads();

  f32x4v acc[9][2];
  const f32x4v z4 = {0.f,0.f,0.f,0.f};
  #pragma unroll
  for(int i=0;i<9;i++){ acc[i][0]=z4; acc[i][1]=z4; }

  #pragma unroll
  for(int ks=0;ks<6;ks++){
    bf16x8v a[2];
    #pragma unroll
    for(int mt=0;mt<2;mt++){
      int row = mt*16 + lm;
      int byte = (row*384 + ks*64 + lh*16) ^ ((row&7)<<4);
      a[mt] = *(const bf16x8v*)((const char*)As + byte);
    }
    #pragma unroll
    for(int i=0;i<9;i++){
      int nt = w*9 + i;
      bf16x8v b = *(const bf16x8v*)(Wp + ((((nt*6 + ks)<<6) + l)<<3));
      acc[i][0] = mfma_bf16(a[0], b, acc[i][0]);
      acc[i][1] = mfma_bf16(a[1], b, acc[i][1]);
    }
  }

  #pragma unroll
  for(int i=0;i<9;i++){
    int n = (w*9 + i)*16 + lm;
    float bv = bias[n];
    #pragma unroll
    for(int mt=0;mt<2;mt++){
      #pragma unroll
      for(int r=0;r<4;r++){
        long mrow = row0 + mt*16 + lh*4 + r;
        float v = acc[i][mt][r] + bv;
        if(n < 192) v *= QSCALE;
        out[mrow*576 + n] = fb(v);
      }
    }
  }
}

// ---------------- fused proj GEMM + residual + LN2 ----------------
__global__ __launch_bounds__(256) void gemm_proj_ln(const u16* __restrict__ A, const u16* __restrict__ Wp,
                                                    const float* __restrict__ bias, const float* __restrict__ resid,
                                                    const float* __restrict__ g, const float* __restrict__ bb,
                                                    u16* __restrict__ x1o, u16* __restrict__ xmo){
  __shared__ u16 As[32*192];
  __shared__ float Vs2[32*200];
  __shared__ long tb_l[32];
  const int tid = threadIdx.x;
  const int w = tid>>6, l = tid&63;
  const int lm = l&15, lh = l>>4;
  const long row0 = (long)blockIdx.x*32;

  if(tid < 32){
    int b_, lt; row_to_token((int)(row0+tid), b_, lt);
    tb_l[tid] = ((long)b_*LTOK + lt)*DIMC;
  }
  {
    const uint4* src = (const uint4*)(A + row0*192);
    #pragma unroll
    for(int c=0;c<3;c++){
      int cz = tid + c*256;
      int row = cz/24;
      int byte = (cz*16) ^ ((row&7)<<4);
      *(uint4*)((char*)As + byte) = src[cz];
    }
  }
  __syncthreads();

  f32x4v acc[3][2];
  const f32x4v z4 = {0.f,0.f,0.f,0.f};
  #pragma unroll
  for(int i=0;i<3;i++){ acc[i][0]=z4; acc[i][1]=z4; }

  #pragma unroll
  for(int ks=0;ks<6;ks++){
    bf16x8v a[2];
    #pragma unroll
    for(int mt=0;mt<2;mt++){
      int row = mt*16 + lm;
      int byte = (row*384 + ks*64 + lh*16) ^ ((row&7)<<4);
      a[mt] = *(const bf16x8v*)((const char*)As + byte);
    }
    #pragma unroll
    for(int i=0;i<3;i++){
      int nt = w*3 + i;
      bf16x8v b = *(const bf16x8v*)(Wp + ((((nt*6 + ks)<<6) + l)<<3));
      acc[i][0] = mfma_bf16(a[0], b, acc[i][0]);
      acc[i][1] = mfma_bf16(a[1], b, acc[i][1]);
    }
  }

  #pragma unroll
  for(int i=0;i<3;i++){
    int n = (w*3 + i)*16 + lm;
    float bv = bias[n];
    #pragma unroll
    for(int mt=0;mt<2;mt++){
      #pragma unroll
      for(int r=0;r<4;r++){
        int row = mt*16 + lh*4 + r;
        Vs2[row*200 + n] = acc[i][mt][r] + bv + resid[tb_l[row] + n];
      }
    }
  }
  __syncthreads();

  for(int rr=0;rr<8;rr++){
    int row = w*8 + rr;
    long tb = tb_l[row];
    const float* pr = &Vs2[row*200];
    float v0 = pr[l], v1 = pr[l+64], v2 = pr[l+128];
    float s = v0+v1+v2;
    #pragma unroll
    for(int m=1;m<64;m<<=1) s += __shfl_xor(s,m);
    float mean = s*(1.f/192.f);
    float d0=v0-mean, d1=v1-mean, d2=v2-mean;
    float q = d0*d0+d1*d1+d2*d2;
    #pragma unroll
    for(int m=1;m<64;m<<=1) q += __shfl_xor(q,m);
    float rstd = rsqrtf(q*(1.f/192.f)+EPSF);
    x1o[tb+l]     = fb(v0);
    x1o[tb+l+64]  = fb(v1);
    x1o[tb+l+128] = fb(v2);
    xmo[tb+l]     = fb(d0*rstd*g[l]     + bb[l]);
    xmo[tb+l+64]  = fb(d1*rstd*g[l+64]  + bb[l+64]);
    xmo[tb+l+128] = fb(d2*rstd*g[l+128] + bb[l+128]);
  }
}

// ---------------- MFMA GEMM (pointwise convs): 32 rows/block, K=192 ----------------
template<int NTOT>
__global__ __launch_bounds__(256) void gemm_mfma(const u16* __restrict__ A, const u16* __restrict__ Wp,
                                                 const float* __restrict__ bias, u16* __restrict__ out){
  constexpr int KS  = 6;
  constexpr int NPW = NTOT/64;
  __shared__ u16 As[32*192];
  const int tid = threadIdx.x;
  const int w = tid>>6, l = tid&63;
  const int lm = l&15, lh = l>>4;
  const long row0 = (long)blockIdx.x*32;

  {
    const uint4* src = (const uint4*)(A + row0*192);
    #pragma unroll
    for(int c=0;c<3;c++){
      int cz = tid + c*256;
      int row = cz/24;
      int byte = (cz*16) ^ ((row&7)<<4);
      *(uint4*)((char*)As + byte) = src[cz];
    }
  }
  __syncthreads();

  f32x4v acc[NPW][2];
  const f32x4v z4 = {0.f,0.f,0.f,0.f};
  #pragma unroll
  for(int i=0;i<NPW;i++){ acc[i][0]=z4; acc[i][1]=z4; }

  #pragma unroll
  for(int ks=0;ks<KS;ks++){
    bf16x8v a[2];
    #pragma unroll
    for(int mt=0;mt<2;mt++){
      int row = mt*16 + lm;
      int byte = (row*384 + ks*64 + lh*16) ^ ((row&7)<<4);
      a[mt] = *(const bf16x8v*)((const char*)As + byte);
    }
    #pragma unroll
    for(int i=0;i<NPW;i++){
      int nt = w*NPW + i;
      bf16x8v b = *(const bf16x8v*)(Wp + ((((nt*KS + ks)<<6) + l)<<3));
      acc[i][0] = mfma_bf16(a[0], b, acc[i][0]);
      acc[i][1] = mfma_bf16(a[1], b, acc[i][1]);
    }
  }

  #pragma unroll
  for(int i=0;i<NPW;i++){
    int n = (w*NPW + i)*16 + lm;
    float bv = bias[n];
    #pragma unroll
    for(int mt=0;mt<2;mt++){
      #pragma unroll
      for(int r=0;r<4;r++){
        long mrow = row0 + mt*16 + lh*4 + r;
        out[mrow*NTOT + n] = fb(acc[i][mt][r] + bv);
      }
    }
  }
}

// ---------------- fused MLP via MFMA (r13-proven, erff GELU): h in 48 KB LDS ----------------
__global__ __launch_bounds__(256) void mlp_mfma(const u16* __restrict__ xm, const u16* __restrict__ Wp1,
                                                const float* __restrict__ b1, const u16* __restrict__ Wp2,
                                                const float* __restrict__ b2, u16* __restrict__ out){
  __shared__ u16 As[32*192];
  __shared__ u16 Hs[32*768];
  const int tid = threadIdx.x;
  const int w = tid>>6, l = tid&63;
  const int lm = l&15, lh = l>>4;
  const long row0 = (long)blockIdx.x*32;

  {
    const uint4* src = (const uint4*)(xm + row0*192);
    #pragma unroll
    for(int c=0;c<3;c++){
      int cz = tid + c*256;
      int row = cz/24;
      int byte = (cz*16) ^ ((row&7)<<4);
      *(uint4*)((char*)As + byte) = src[cz];
    }
  }
  __syncthreads();

  const f32x4v z4 = {0.f,0.f,0.f,0.f};
  f32x4v acc1[12][2];
  #pragma unroll
  for(int i=0;i<12;i++){ acc1[i][0]=z4; acc1[i][1]=z4; }

  #pragma unroll
  for(int ks=0;ks<6;ks++){
    bf16x8v a[2];
    #pragma unroll
    for(int mt=0;mt<2;mt++){
      int row = mt*16 + lm;
      int byte = (row*384 + ks*64 + lh*16) ^ ((row&7)<<4);
      a[mt] = *(const bf16x8v*)((const char*)As + byte);
    }
    #pragma unroll
    for(int i=0;i<12;i++){
      int nt = w*12 + i;
      bf16x8v b = *(const bf16x8v*)(Wp1 + ((((nt*6 + ks)<<6) + l)<<3));
      acc1[i][0] = mfma_bf16(a[0], b, acc1[i][0]);
      acc1[i][1] = mfma_bf16(a[1], b, acc1[i][1]);
    }
  }

  #pragma unroll
  for(int i=0;i<12;i++){
    int n = (w*12 + i)*16 + lm;
    float bv = b1[n];
    #pragma unroll
    for(int mt=0;mt<2;mt++){
      #pragma unroll
      for(int r=0;r<4;r++){
        int mrow = mt*16 + lh*4 + r;
        float h = gelu_f(acc1[i][mt][r] + bv);
        int byte = (mrow*1536 + n*2) ^ ((mrow&7)<<4);
        *(u16*)((char*)Hs + byte) = fb(h);
      }
    }
  }
  __syncthreads();

  f32x4v acc2[3][2];
  #pragma unroll
  for(int i=0;i<3;i++){ acc2[i][0]=z4; acc2[i][1]=z4; }

  #pragma unroll 4
  for(int ks=0;ks<24;ks++){
    bf16x8v a[2];
    #pragma unroll
    for(int mt=0;mt<2;mt++){
      int row = mt*16 + lm;
      int byte = (row*1536 + ks*64 + lh*16) ^ ((row&7)<<4);
      a[mt] = *(const bf16x8v*)((const char*)Hs + byte);
    }
    #pragma unroll
    for(int i=0;i<3;i++){
      int nt = w*3 + i;
      bf16x8v b = *(const bf16x8v*)(Wp2 + ((((nt*24 + ks)<<6) + l)<<3));
      acc2[i][0] = mfma_bf16(a[0], b, acc2[i][0]);
      acc2[i][1] = mfma_bf16(a[1], b, acc2[i][1]);
    }
  }

  #pragma unroll
  for(int i=0;i<3;i++){
    int n = (w*3 + i)*16 + lm;
    float bv = b2[n];
    #pragma unroll
    for(int mt=0;mt<2;mt++){
      #pragma unroll
      for(int r=0;r<4;r++){
        long mrow = row0 + mt*16 + lh*4 + r;
        out[mrow*192 + n] = fb(acc2[i][mt][r] + bv);
      }
    }
  }
}

// ---------------- MFMA attention v3' ----------------
__global__ __launch_bounds__(256) void attn_mfma(const u16* __restrict__ qkv, const float* __restrict__ rpb,
                                                 u16* __restrict__ out){
  __shared__ u16 Kf[22*512];
  __shared__ u16 Vt[32*360];
  __shared__ u16 Ps[4][16*200];
  __shared__ u16 rpb_l[2198];
  __shared__ u32 lin_l[352];

  const int tid = threadIdx.x;
  const int bw = blockIdx.x / 6, hh = blockIdx.x % 6;
  const int wi = bw & 63;
  const long rowbase = (long)bw*NWIN;

  for(int i=tid;i<2197;i+=256) rpb_l[i] = fb(rpb[i*6+hh]);
  for(int i2=tid;i2<352;i2+=256){
    u32 v = 0x7FFF0000u;
    if(i2 < 343){
      int jz = i2/49, jr = i2-jz*49, jy = jr/7, jx = jr-jy*7;
      int sd = (wi>>4)*7 + jz, sh2 = ((wi>>2)&3)*7 + jy, sw = (wi&3)*7 + jx;
      int rd = sd<21?0:(sd<25?1:2);
      int rh = sh2<21?0:(sh2<25?1:2);
      int rw = sw<21?0:(sw<25?1:2);
      v = (u32)(jz*169 + jy*13 + jx) | ((u32)(rd*9+rh*3+rw)<<16);
    }
    lin_l[i2] = v;
  }
  for(int p2=tid;p2<288;p2+=256){
    int d = p2/9, j = 343 + p2%9; Vt[d*360 + j] = 0;
  }
  ((u32*)Kf)[21*256 + tid] = 0;
  __syncthreads();

  for(int p = tid; p < 343*16; p += 256){
    int j = p >> 4, dp = p & 15;
    const u32* src = (const u32*)(qkv + (rowbase + j)*576 + hh*32) + dp;
    u32 kk = src[96];
    u32 vv = src[192];
    ((u32*)Kf)[(j>>4)*256 + ((dp>>2)*16 + (j&15))*4 + (dp&3)] = kk;
    Vt[(dp*2)*360 + j]   = (u16)(vv & 0xffffu);
    Vt[(dp*2+1)*360 + j] = (u16)(vv >> 16);
  }
  __syncthreads();

  const int w = tid>>6, l = tid&63;
  const int lm = l&15, lh = l>>4;
  u16* Pw = Ps[w];
  const f32x4v z4 = {0.f,0.f,0.f,0.f};

  for(int it = w; it < 22; it += 4){
    const int i0 = it*16;
    bf16x8v aq = *(const bf16x8v*)(qkv + (rowbase + i0 + lm)*576 + hh*32 + lh*8);

    f32x4v acc[22];
    #pragma unroll
    for(int jt=0;jt<22;jt++){
      bf16x8v bk = *(const bf16x8v*)(Kf + jt*512 + l*8);
      acc[jt] = mfma_bf16(aq, bk, z4);
    }

    int lia[4]; u32 lir[4];
    #pragma unroll
    for(int r=0;r<4;r++){
      int i = i0 + lh*4 + r; if(i>342) i=342;
      u32 t = lin_l[i];
      lia[r] = (int)(t & 0xffffu) + 1098;
      lir[r] = t >> 16;
    }
    #pragma unroll
    for(int jt=0;jt<22;jt++){
      u32 lj = lin_l[jt*16 + lm];
      int ljl = (int)(lj & 0xffffu); u32 ljr = lj >> 16;
      #pragma unroll
      for(int r=0;r<4;r++){
        int idx = lia[r] - ljl;
        acc[jt][r] = acc[jt][r] + bu(rpb_l[idx]) + ((lir[r]==ljr) ? 0.f : -100.f);
      }
    }

    float rinv[4];
    #pragma unroll
    for(int r=0;r<4;r++){
      float sm = 0.f;
      #pragma unroll
      for(int jt=0;jt<22;jt++){ float e = __expf(acc[jt][r]); acc[jt][r]=e; sm += e; }
      #pragma unroll
      for(int m=1;m<16;m<<=1) sm += __shfl_xor(sm, m);
      rinv[r] = 1.0f/sm;
    }

    f32x4v o0=z4, o1=z4;
    #pragma unroll
    for(int jt=0;jt<12;jt++){
      int jl = jt*16 + lm;
      #pragma unroll
      for(int r=0;r<4;r++) Pw[(lh*4+r)*200 + jl] = fb(acc[jt][r]);
    }
    #pragma unroll
    for(int ks=0;ks<6;ks++){
      bf16x8v ap = *(const bf16x8v*)(Pw + lm*200 + ks*32 + lh*8);
      bf16x8v b0 = *(const bf16x8v*)(Vt + lm*360 + ks*32 + lh*8);
      bf16x8v b1 = *(const bf16x8v*)(Vt + (16+lm)*360 + ks*32 + lh*8);
      o0 = mfma_bf16(ap, b0, o0);
      o1 = mfma_bf16(ap, b1, o1);
    }
    #pragma unroll
    for(int jt=12;jt<22;jt++){
      int jl = jt*16 + lm - 192;
      #pragma unroll
      for(int r=0;r<4;r++) Pw[(lh*4+r)*200 + jl] = fb(acc[jt][r]);
    }
    #pragma unroll
    for(int ks=0;ks<5;ks++){
      bf16x8v ap = *(const bf16x8v*)(Pw + lm*200 + ks*32 + lh*8);
      bf16x8v b0 = *(const bf16x8v*)(Vt + lm*360 + 192 + ks*32 + lh*8);
      bf16x8v b1 = *(const bf16x8v*)(Vt + (16+lm)*360 + 192 + ks*32 + lh*8);
      o0 = mfma_bf16(ap, b0, o0);
      o1 = mfma_bf16(ap, b1, o1);
    }

    #pragma unroll
    for(int r=0;r<4;r++){
      int i = i0 + lh*4 + r;
      if(i < 343){
        u16* po = out + (rowbase + i)*192 + hh*32;
        po[lm]    = fb(o0[r]*rinv[r]);
        po[16+lm] = fb(o1[r]*rinv[r]);
      }
    }
  }
}

// ---------------- depthwise 3x3x3 conv, x-blocked: 4 outputs x 8 ch per thread ----------------
__global__ __launch_bounds__(256) void dw3v4(const u16* __restrict__ in, const float* __restrict__ kwT,
                                             const float* __restrict__ bias, u16* __restrict__ out){
  __shared__ float wls[5184];
  const int tid = threadIdx.x;
  for(int i=tid;i<5184;i+=256) wls[i] = kwT[i];
  __syncthreads();

  int gid = blockIdx.x*256 + tid;
  int c8 = gid % 24;
  int t  = gid / 24;
  int b  = t / 5488; int s = t - b*5488;
  int z  = s / 196;  int r = s - z*196;
  int y  = r / 7;    int x4 = r - y*7;
  int x0 = x4*4;

  float acc[4][8];
  {
    const float4* bp = (const float4*)(bias + c8*8);
    float4 b0 = bp[0], b1 = bp[1];
    #pragma unroll
    for(int xi=0;xi<4;xi++){
      acc[xi][0]=b0.x; acc[xi][1]=b0.y; acc[xi][2]=b0.z; acc[xi][3]=b0.w;
      acc[xi][4]=b1.x; acc[xi][5]=b1.y; acc[xi][6]=b1.z; acc[xi][7]=b1.w;
    }
  }

  #pragma unroll
  for(int dz=-1;dz<=1;dz++){
    int zz=z+dz; if((unsigned)zz>=28u) continue;
    #pragma unroll
    for(int dy=-1;dy<=1;dy++){
      int yy=y+dy; if((unsigned)yy>=28u) continue;
      const u16* rowp = in + (((long)b*LTOK + zz*784 + yy*28)*192) + c8*8;
      uint4 v[6];
      #pragma unroll
      for(int xc=0;xc<6;xc++){
        int xx = x0 + xc - 1;
        if((unsigned)xx < 28u) v[xc] = *(const uint4*)(rowp + (long)xx*192);
        else { v[xc].x=0; v[xc].y=0; v[xc].z=0; v[xc].w=0; }
      }
      #pragma unroll
      for(int dxi=0;dxi<3;dxi++){
        int tap = (dz+1)*9+(dy+1)*3+dxi;
        const float* wp = &wls[tap*192 + c8*8];
        float4 w0 = *(const float4*)wp;
        float4 w1 = *(const float4*)(wp+4);
        #pragma unroll
        for(int xi=0;xi<4;xi++){
          uint4 vv = v[xi+dxi];
          acc[xi][0] = fmaf(lo16(vv.x), w0.x, acc[xi][0]);
          acc[xi][1] = fmaf(hi16(vv.x), w0.y, acc[xi][1]);
          acc[xi][2] = fmaf(lo16(vv.y), w0.z, acc[xi][2]);
          acc[xi][3] = fmaf(hi16(vv.y), w0.w, acc[xi][3]);
          acc[xi][4] = fmaf(lo16(vv.z), w1.x, acc[xi][4]);
          acc[xi][5] = fmaf(hi16(vv.z), w1.y, acc[xi][5]);
          acc[xi][6] = fmaf(lo16(vv.w), w1.z, acc[xi][6]);
          acc[xi][7] = fmaf(hi16(vv.w), w1.w, acc[xi][7]);
        }
      }
    }
  }

  u16* op = out + (((long)b*LTOK + z*784 + y*28 + x0)*192) + c8*8;
  #pragma unroll
  for(int xi=0;xi<4;xi++){
    uint4 o;
    o.x = ((u32)fb(acc[xi][1])<<16) | fb(acc[xi][0]);
    o.y = ((u32)fb(acc[xi][3])<<16) | fb(acc[xi][2]);
    o.z = ((u32)fb(acc[xi][5])<<16) | fb(acc[xi][4]);
    o.w = ((u32)fb(acc[xi][7])<<16) | fb(acc[xi][6]);
    *(uint4*)(op + (long)xi*192) = o;
  }
}

// ---------------- final: x1 + lin + NCDHW-view gather of t2 -> f32 out (8 elem/thread) ----------------
__global__ __launch_bounds__(256) void final_add(const u16* __restrict__ x1, const u16* __restrict__ lin,
                                                 const u16* __restrict__ t2, float* __restrict__ out){
  int g8 = blockIdx.x*256 + threadIdx.x;
  int gid0 = g8*8;
  int b  = gid0 / 4214784;
  int gg = gid0 - b*4214784;
  int ch = gg / LTOK;
  int sp = gg - ch*LTOK;
  uint4 xa = *(const uint4*)(x1 + gid0);
  uint4 la = *(const uint4*)(lin + gid0);
  const u16* tp = t2 + ((long)b*LTOK + sp)*192 + ch;
  float4 o0, o1;
  o0.x = lo16(xa.x) + lo16(la.x) + bu(tp[0*192]);
  o0.y = hi16(xa.x) + hi16(la.x) + bu(tp[1*192]);
  o0.z = lo16(xa.y) + lo16(la.y) + bu(tp[2*192]);
  o0.w = hi16(xa.y) + hi16(la.y) + bu(tp[3*192]);
  o1.x = lo16(xa.z) + lo16(la.z) + bu(tp[4*192]);
  o1.y = hi16(xa.z) + hi16(la.z) + bu(tp[5*192]);
  o1.z = lo16(xa.w) + lo16(la.w) + bu(tp[6*192]);
  o1.w = hi16(xa.w) + hi16(la.w) + bu(tp[7*192]);
  *(float4*)(out + gid0)     = o0;
  *(float4*)(out + gid0 + 4) = o1;
}

extern "C" void kernel_launch(void* const* d_in, const int* in_sizes, int n_in,
                              void* d_out, int out_size, void* d_ws, size_t ws_size,
                              hipStream_t stream){
  const float* x      = (const float*)d_in[0];
  const float* n1g    = (const float*)d_in[2];
  const float* n1b    = (const float*)d_in[3];
  const float* qkv_w  = (const float*)d_in[4];
  const float* qkv_b  = (const float*)d_in[5];
  const float* rpb    = (const float*)d_in[6];
  const float* proj_w = (const float*)d_in[7];
  const float* proj_b = (const float*)d_in[8];
  const float* n2g    = (const float*)d_in[9];
  const float* n2b    = (const float*)d_in[10];
  const float* l1w    = (const float*)d_in[11];
  const float* l1b    = (const float*)d_in[12];
  const float* l2w    = (const float*)d_in[13];
  const float* l2b    = (const float*)d_in[14];
  const float* dw1k   = (const float*)d_in[15];
  const float* dw1b   = (const float*)d_in[16];
  const float* pw1k   = (const float*)d_in[17];
  const float* pw1b   = (const float*)d_in[18];
  const float* dw2k   = (const float*)d_in[19];
  const float* dw2b   = (const float*)d_in[20];
  const float* pw2k   = (const float*)d_in[21];
  const float* pw2b   = (const float*)d_in[22];

  const size_t FB = (size_t)ROWSZ * DIMC;
  u16* x1b   = (u16*)d_ws;
  u16* xmb   = x1b + FB;
  u16* attnb = xmb + FB;
  u16* qkvb  = attnb + FB;      // 3*FB
  u16* cb1   = qkvb;
  u16* cb2   = qkvb + FB;
  u16* linb  = attnb;
  u16* pk_qkv  = x1b + 6*FB;
  u16* pk_proj = pk_qkv  + 110592;
  u16* pk_l1   = pk_proj + 36864;
  u16* pk_l2   = pk_l1   + 147456;
  u16* pk_pw1  = pk_l2   + 147456;
  u16* pk_pw2  = pk_pw1  + 36864;
  float* kwT1  = (float*)(pk_pw2 + 36864);   // 5184 f32
  float* kwT2  = kwT1 + 5184;

  pack_w<0><<<432,256,0,stream>>>(qkv_w,  pk_qkv,  192, 576);
  pack_w<0><<<144,256,0,stream>>>(proj_w, pk_proj, 192, 192);
  pack_w<0><<<576,256,0,stream>>>(l1w,    pk_l1,   192, 768);
  pack_w<0><<<576,256,0,stream>>>(l2w,    pk_l2,   768, 192);
  pack_w<1><<<144,256,0,stream>>>(pw1k,   pk_pw1,  192, 192);
  pack_w<1><<<144,256,0,stream>>>(pw2k,   pk_pw2,  192, 192);
  pack_dwk<<<21,256,0,stream>>>(dw1k, dw2k, kwT1, kwT2);

  gemm_qkv_ln<<<ROWSZ/32,256,0,stream>>>(x, n1g, n1b, pk_qkv, qkv_b, qkvb);
  attn_mfma<<<128*6,256,0,stream>>>(qkvb, rpb, attnb);
  gemm_proj_ln<<<ROWSZ/32,256,0,stream>>>(attnb, pk_proj, proj_b, x, n2g, n2b, x1b, xmb);
  mlp_mfma<<<ROWSZ/32,256,0,stream>>>(xmb, pk_l1, l1b, pk_l2, l2b, linb);
  dw3v4<<<1029,256,0,stream>>>(xmb, kwT1, dw1b, cb1);
  gemm_mfma<192><<<ROWSZ/32,256,0,stream>>>(cb1, pk_pw1, pw1b, cb2);
  dw3v4<<<1029,256,0,stream>>>(cb2, kwT2, dw2b, cb1);
  gemm_mfma<192><<<ROWSZ/32,256,0,stream>>>(cb1, pk_pw2, pw2b, cb2);
  final_add<<<TOTE/2048,256,0,stream>>>(x1b, linb, cb2, (float*)d_out);
}